// Round 3
// baseline (2478.712 us; speedup 1.0000x reference)
//
#include <hip/hip_runtime.h>

#define NN 100000
#define NE 1600000
#define NE2 1700000
#define OUT_EI 3200000
#define OUT_AL 6600000
#define SLOPE 0.2f

typedef unsigned short u16;
typedef unsigned int u32;
typedef __bf16 bf16x8 __attribute__((ext_vector_type(8)));
typedef float f32x4 __attribute__((ext_vector_type(4)));

__device__ __forceinline__ float bf2f(u16 u){ return __uint_as_float(((u32)u) << 16); }
__device__ __forceinline__ u16 f2bf(float f){
    u32 x = __float_as_uint(f);
    x += 0x7FFFu + ((x >> 16) & 1u);   // round-to-nearest-even
    return (u16)(x >> 16);
}
__device__ __forceinline__ float eluf(float v){ return v > 0.f ? v : (expf(v) - 1.f); }
__device__ __forceinline__ float lreluf(float v){ return v > 0.f ? v : SLOPE * v; }
// adaptive load: flag==1 -> buffer is fp32, else bf16
__device__ __forceinline__ float loadf(const void* p, int i, int f){
    return f ? ((const float*)p)[i] : bf2f(((const u16*)p)[i]);
}

// ---- dtype probe: bf16 NaN/Inf bit pattern only occurs if buffer is really fp32 ----
__global__ __launch_bounds__(256) void k_flag(const u16* __restrict__ x, int* __restrict__ flag){
    int i = blockIdx.x * 256 + threadIdx.x;          // NN*128 exact
    u16 v = x[i];
    if ((v & 0x7F80u) == 0x7F80u) atomicOr(flag, 1);
}

// ---- degree + incoming edge-attr sum (for self-loop mean attr) ----
__global__ __launch_bounds__(256) void k_prep(const int* __restrict__ ei, const void* __restrict__ eattr,
                                              const int* __restrict__ flagp,
                                              float* __restrict__ deg, float* __restrict__ attr_sum){
    int f = *flagp;
    int t = blockIdx.x * 256 + threadIdx.x;          // NE*16 exact
    int e = t >> 4, j = t & 15;
    int dst = ei[NE + e];
    unsafeAtomicAdd(&attr_sum[dst * 16 + j], loadf(eattr, e * 16 + j, f));
    if (j == 0) unsafeAtomicAdd(&deg[dst], 1.f);
}

// ---- q1[k*4+h] = sum_c W1e[k,h*32+c]*a1e[h,c]; q2[k] = sum_c W2e[k,c]*a2e[c] ----
__global__ void k_q(const void* __restrict__ W1e, const void* __restrict__ a1e,
                    const void* __restrict__ W2e, const void* __restrict__ a2e,
                    const int* __restrict__ flagp,
                    float* __restrict__ q1, float* __restrict__ q2){
    int f = *flagp;
    int t = threadIdx.x;           // 64 threads
    int k = t >> 2, h = t & 3;
    float s = 0.f;
    for (int c = 0; c < 32; c++) s += loadf(W1e, k * 128 + h * 32 + c, f) * loadf(a1e, h * 32 + c, f);
    q1[t] = s;
    if (t < 16){
        float s2 = 0.f;
        for (int c = 0; c < 32; c++) s2 += loadf(W2e, t * 32 + c, f) * loadf(a2e, c, f);
        q2[t] = s2;
    }
}

// ---- GEMM1: h1[N,128] = x[N,128] @ W1[128,128] -> bf16 (MFMA 16x16x32) ----
__global__ __launch_bounds__(256) void k_gemm1(const void* __restrict__ x, const void* __restrict__ W,
                                               const int* __restrict__ flagp, u16* __restrict__ h1){
    __shared__ __align__(16) u16 sW[128 * 136];  // transposed: sW[col*136+k]
    int f = *flagp;
    int t = threadIdx.x;
    if (f){
        const float* Wf = (const float*)W;
        for (int i = t; i < 128 * 128; i += 256){
            int k = i >> 7, c = i & 127;
            sW[c * 136 + k] = f2bf(Wf[i]);
        }
    } else {
        const u16* Wb = (const u16*)W;
        for (int i = t; i < 128 * 128; i += 256){
            int k = i >> 7, c = i & 127;
            sW[c * 136 + k] = Wb[i];
        }
    }
    __syncthreads();
    int lane = t & 63, wave = t >> 6;
    int quad = lane >> 4, m16 = lane & 15;
    int rowA = blockIdx.x * 64 + wave * 16 + m16;
    bf16x8 afr[4];
    if (rowA < NN){
        if (f){
            const float* xr = (const float*)x + rowA * 128 + quad * 8;
            #pragma unroll
            for (int kk = 0; kk < 4; kk++)
                #pragma unroll
                for (int i = 0; i < 8; i++) afr[kk][i] = (__bf16)xr[kk * 32 + i];
        } else {
            const u16* xr = (const u16*)x + rowA * 128 + quad * 8;
            #pragma unroll
            for (int kk = 0; kk < 4; kk++) afr[kk] = *(const bf16x8*)(xr + kk * 32);
        }
    } else {
        #pragma unroll
        for (int kk = 0; kk < 4; kk++)
            #pragma unroll
            for (int i = 0; i < 8; i++) afr[kk][i] = (__bf16)0.f;
    }
    int rowbase = blockIdx.x * 64 + wave * 16 + quad * 4;
    #pragma unroll
    for (int nt = 0; nt < 8; nt++){
        f32x4 acc = (f32x4){0.f, 0.f, 0.f, 0.f};
        const u16* wp = &sW[(nt * 16 + m16) * 136 + quad * 8];
        #pragma unroll
        for (int kk = 0; kk < 4; kk++){
            bf16x8 bfr = *(const bf16x8*)(wp + kk * 32);
            acc = __builtin_amdgcn_mfma_f32_16x16x32_bf16(afr[kk], bfr, acc, 0, 0, 0);
        }
        int col = nt * 16 + m16;
        #pragma unroll
        for (int r = 0; r < 4; r++){
            int row = rowbase + r;
            if (row < NN) h1[row * 128 + col] = f2bf(acc[r]);
        }
    }
}

// ---- GEMM2: h2a[N,32] = h1[N,128] @ W2[128,32] -> f32 ----
__global__ __launch_bounds__(256) void k_gemm2(const u16* __restrict__ hin, const void* __restrict__ W,
                                               const int* __restrict__ flagp, float* __restrict__ h2a){
    __shared__ __align__(16) u16 sW[32 * 136];
    int f = *flagp;
    int t = threadIdx.x;
    if (f){
        const float* Wf = (const float*)W;
        for (int i = t; i < 128 * 32; i += 256){
            int k = i >> 5, c = i & 31;
            sW[c * 136 + k] = f2bf(Wf[i]);
        }
    } else {
        const u16* Wb = (const u16*)W;
        for (int i = t; i < 128 * 32; i += 256){
            int k = i >> 5, c = i & 31;
            sW[c * 136 + k] = Wb[i];
        }
    }
    __syncthreads();
    int lane = t & 63, wave = t >> 6;
    int quad = lane >> 4, m16 = lane & 15;
    int rowA = blockIdx.x * 64 + wave * 16 + m16;
    bf16x8 afr[4];
    if (rowA < NN){
        const u16* xr = hin + rowA * 128 + quad * 8;
        #pragma unroll
        for (int kk = 0; kk < 4; kk++) afr[kk] = *(const bf16x8*)(xr + kk * 32);
    } else {
        #pragma unroll
        for (int kk = 0; kk < 4; kk++)
            #pragma unroll
            for (int i = 0; i < 8; i++) afr[kk][i] = (__bf16)0.f;
    }
    int rowbase = blockIdx.x * 64 + wave * 16 + quad * 4;
    #pragma unroll
    for (int nt = 0; nt < 2; nt++){
        f32x4 acc = (f32x4){0.f, 0.f, 0.f, 0.f};
        const u16* wp = &sW[(nt * 16 + m16) * 136 + quad * 8];
        #pragma unroll
        for (int kk = 0; kk < 4; kk++){
            bf16x8 bfr = *(const bf16x8*)(wp + kk * 32);
            acc = __builtin_amdgcn_mfma_f32_16x16x32_bf16(afr[kk], bfr, acc, 0, 0, 0);
        }
        int col = nt * 16 + m16;
        #pragma unroll
        for (int r = 0; r < 4; r++){
            int row = rowbase + r;
            if (row < NN) h2a[row * 32 + col] = acc[r];
        }
    }
}

// ---- per-node attention logits layer1 ----
__global__ __launch_bounds__(256) void k_al1(const u16* __restrict__ h1, const void* __restrict__ a1s,
                                             const void* __restrict__ a1d, const int* __restrict__ flagp,
                                             float* __restrict__ al_s, float* __restrict__ al_d){
    int f = *flagp;
    int idx = blockIdx.x * 256 + threadIdx.x;   // NN*128 exact
    int j = idx & 127;
    float v = bf2f(h1[idx]);
    float vs = v * loadf(a1s, j, f);
    float vd = v * loadf(a1d, j, f);
    #pragma unroll
    for (int m = 1; m < 32; m <<= 1){ vs += __shfl_xor(vs, m); vd += __shfl_xor(vd, m); }
    if ((threadIdx.x & 31) == 0){
        int n = idx >> 7, h = j >> 5;
        al_s[n * 4 + h] = vs;
        al_d[n * 4 + h] = vd;
    }
}

__global__ __launch_bounds__(256) void k_al2(const float* __restrict__ h2a, const void* __restrict__ a2s,
                                             const void* __restrict__ a2d, const int* __restrict__ flagp,
                                             float* __restrict__ al_s, float* __restrict__ al_d){
    int f = *flagp;
    int idx = blockIdx.x * 256 + threadIdx.x;   // NN*32 exact
    int c = idx & 31;
    float v = h2a[idx];
    float vs = v * loadf(a2s, c, f);
    float vd = v * loadf(a2d, c, f);
    #pragma unroll
    for (int m = 1; m < 32; m <<= 1){ vs += __shfl_xor(vs, m); vd += __shfl_xor(vd, m); }
    if ((threadIdx.x & 31) == 0){
        int n = idx >> 5;
        al_s[n] = vs;
        al_d[n] = vd;
    }
}

// ---- layer1 softmax denominator: z1[dst,h] += exp(lrelu(...)) ----
__global__ __launch_bounds__(256) void k_edge_z1(const int* __restrict__ ei, const void* __restrict__ eattr,
                                                 const int* __restrict__ flagp,
                                                 const float* __restrict__ attr_sum, const float* __restrict__ deg,
                                                 const float* __restrict__ q1,
                                                 const float* __restrict__ al_s, const float* __restrict__ al_d,
                                                 float* __restrict__ z1){
    int f = *flagp;
    int t = blockIdx.x * 256 + threadIdx.x;    // NE2*16 exact
    int e = t >> 4, j = t & 15;
    int src, dst; float attr;
    if (e < NE){
        src = ei[e]; dst = ei[NE + e];
        attr = loadf(eattr, e * 16 + j, f);
    } else {
        int n = e - NE; src = n; dst = n;
        attr = attr_sum[n * 16 + j] / fmaxf(deg[n], 1.f);
    }
    float v0 = attr * q1[j * 4 + 0];
    float v1 = attr * q1[j * 4 + 1];
    float v2 = attr * q1[j * 4 + 2];
    float v3 = attr * q1[j * 4 + 3];
    #pragma unroll
    for (int m = 1; m < 16; m <<= 1){
        v0 += __shfl_xor(v0, m); v1 += __shfl_xor(v1, m);
        v2 += __shfl_xor(v2, m); v3 += __shfl_xor(v3, m);
    }
    if (j < 4){
        float ale = (j == 0) ? v0 : (j == 1) ? v1 : (j == 2) ? v2 : v3;
        float p = expf(lreluf(al_s[src * 4 + j] + al_d[dst * 4 + j] + ale));
        unsafeAtomicAdd(&z1[dst * 4 + j], p);
    }
}

// ---- layer1 aggregate (recomputes p): out1[dst,:] += alpha * h1[src,:] ----
__global__ __launch_bounds__(256) void k_edge_agg1(const int* __restrict__ ei, const void* __restrict__ eattr,
                                                   const int* __restrict__ flagp,
                                                   const float* __restrict__ attr_sum, const float* __restrict__ deg,
                                                   const float* __restrict__ q1,
                                                   const float* __restrict__ al_s, const float* __restrict__ al_d,
                                                   const float* __restrict__ z1,
                                                   const u16* __restrict__ h1, float* __restrict__ out1){
    int f = *flagp;
    int wave = threadIdx.x >> 6, lane = threadIdx.x & 63;
    int e = blockIdx.x * 4 + wave;             // NE2/4 exact
    int j = lane >> 2, h = lane & 3;           // lane = j*4+h
    int src, dst; float attr;
    if (e < NE){
        src = ei[e]; dst = ei[NE + e];
        attr = loadf(eattr, e * 16 + j, f);
    } else {
        int n = e - NE; src = n; dst = n;
        attr = attr_sum[n * 16 + j] / fmaxf(deg[n], 1.f);
    }
    float v = attr * q1[lane];                 // q1 layout [j*4+h]
    #pragma unroll
    for (int m = 4; m < 64; m <<= 1) v += __shfl_xor(v, m);   // reduce over j, keep h
    float ev = lreluf(al_s[src * 4 + h] + al_d[dst * 4 + h] + v);
    float alpha = expf(ev) / z1[dst * 4 + h];
    float a = __shfl(alpha, lane >> 4);        // head of channels 2*lane, 2*lane+1
    u32 hv = ((const u32*)(h1 + src * 128))[lane];
    int c0 = dst * 128 + lane * 2;
    unsafeAtomicAdd(&out1[c0],     a * bf2f((u16)(hv & 0xFFFFu)));
    unsafeAtomicAdd(&out1[c0 + 1], a * bf2f((u16)(hv >> 16)));
}

// ---- h1 = elu(out1 + b1) -> bf16 in place ----
__global__ __launch_bounds__(256) void k_elu1(const float* __restrict__ out1, const void* __restrict__ b1,
                                              const int* __restrict__ flagp, u16* __restrict__ h1){
    int f = *flagp;
    int idx = blockIdx.x * 256 + threadIdx.x;  // NN*128 exact
    float v = out1[idx] + loadf(b1, idx & 127, f);
    h1[idx] = f2bf(eluf(v));
}

// ---- layer2 softmax denominator ----
__global__ __launch_bounds__(256) void k_edge_z2(const int* __restrict__ ei, const void* __restrict__ eattr,
                                                 const int* __restrict__ flagp,
                                                 const float* __restrict__ attr_sum, const float* __restrict__ deg,
                                                 const float* __restrict__ q2,
                                                 const float* __restrict__ al_s, const float* __restrict__ al_d,
                                                 float* __restrict__ z2){
    int f = *flagp;
    int t = blockIdx.x * 256 + threadIdx.x;    // NE2*16 exact
    int e = t >> 4, j = t & 15;
    int src, dst; float attr;
    if (e < NE){
        src = ei[e]; dst = ei[NE + e];
        attr = loadf(eattr, e * 16 + j, f);
    } else {
        int n = e - NE; src = n; dst = n;
        attr = attr_sum[n * 16 + j] / fmaxf(deg[n], 1.f);
    }
    float v = attr * q2[j];
    #pragma unroll
    for (int m = 1; m < 16; m <<= 1) v += __shfl_xor(v, m);
    if (j == 0){
        float p = expf(lreluf(al_s[src] + al_d[dst] + v));
        unsafeAtomicAdd(&z2[dst], p);
    }
}

// ---- layer2 aggregate (recomputes p) + alpha2 output (f32); 32 lanes per edge ----
__global__ __launch_bounds__(256) void k_edge_agg2(const int* __restrict__ ei, const void* __restrict__ eattr,
                                                   const int* __restrict__ flagp,
                                                   const float* __restrict__ attr_sum, const float* __restrict__ deg,
                                                   const float* __restrict__ q2,
                                                   const float* __restrict__ al_s, const float* __restrict__ al_d,
                                                   const float* __restrict__ z2,
                                                   const float* __restrict__ h2a,
                                                   float* __restrict__ out2, float* __restrict__ dout){
    int f = *flagp;
    int g = threadIdx.x >> 5;
    int e = blockIdx.x * 8 + g;                // NE2/8 exact
    int c = threadIdx.x & 31, j = c & 15;
    int src, dst; float attr;
    if (e < NE){
        src = ei[e]; dst = ei[NE + e];
        attr = loadf(eattr, e * 16 + j, f);
    } else {
        int n = e - NE; src = n; dst = n;
        attr = attr_sum[n * 16 + j] / fmaxf(deg[n], 1.f);
    }
    float v = attr * q2[j];
    #pragma unroll
    for (int m = 1; m < 16; m <<= 1) v += __shfl_xor(v, m);   // both 16-subgroups compute same sum
    float alpha = expf(lreluf(al_s[src] + al_d[dst] + v)) / z2[dst];
    unsafeAtomicAdd(&out2[dst * 32 + c], alpha * h2a[src * 32 + c]);
    if (c == 0) dout[OUT_AL + e] = alpha;
}

// ---- h2 = elu(out2 + b2) -> d_out (f32) ----
__global__ __launch_bounds__(256) void k_final(const float* __restrict__ out2, const void* __restrict__ b2,
                                               const int* __restrict__ flagp, float* __restrict__ dout){
    int f = *flagp;
    int idx = blockIdx.x * 256 + threadIdx.x;  // NN*32 exact
    float v = out2[idx] + loadf(b2, idx & 31, f);
    dout[idx] = eluf(v);
}

// ---- edge_index_sl output (f32 values) ----
__global__ __launch_bounds__(256) void k_eidx(const int* __restrict__ ei, float* __restrict__ dout){
    int i = blockIdx.x * 256 + threadIdx.x;
    if (i >= 2 * NE2) return;
    int val;
    if (i < NE2) val = (i < NE) ? ei[i] : (i - NE);
    else { int e = i - NE2; val = (e < NE) ? ei[NE + e] : (e - NE); }
    dout[OUT_EI + i] = (float)val;
}

extern "C" void kernel_launch(void* const* d_in, const int* in_sizes, int n_in,
                              void* d_out, int out_size, void* d_ws, size_t ws_size,
                              hipStream_t stream) {
    const void* x     = d_in[0];
    const int*  ei    = (const int*)d_in[1];
    const void* eattr = d_in[2];
    const void* W1    = d_in[3];
    const void* W1e   = d_in[4];
    const void* a1s   = d_in[5];
    const void* a1d   = d_in[6];
    const void* a1e   = d_in[7];
    const void* b1    = d_in[8];
    const void* W2    = d_in[9];
    const void* W2e   = d_in[10];
    const void* a2s   = d_in[11];
    const void* a2d   = d_in[12];
    const void* a2e   = d_in[13];
    const void* b2    = d_in[14];
    float* dout = (float*)d_out;

    char* ws = (char*)d_ws;
    size_t off = 0;
    auto alloc = [&](size_t bytes) -> void* {
        void* p = ws + off;
        off += (bytes + 255) & ~(size_t)255;
        return p;
    };
    // --- zero-initialized region (one memset) ---
    int*   flag     = (int*)alloc(256);
    float* deg      = (float*)alloc((size_t)NN * 4);
    float* attr_sum = (float*)alloc((size_t)NN * 16 * 4);
    float* z1       = (float*)alloc((size_t)NN * 4 * 4);
    float* out1     = (float*)alloc((size_t)NN * 128 * 4);
    size_t zero_bytes = off;
    // --- rest (fully written before read) ---
    u16*   h1    = (u16*)alloc((size_t)NN * 128 * 2);
    float* al_s1 = (float*)alloc((size_t)NN * 4 * 4);
    float* al_d1 = (float*)alloc((size_t)NN * 4 * 4);
    float* q1    = (float*)alloc(64 * 4);
    float* q2    = (float*)alloc(16 * 4);
    // --- layer-2 buffers aliased into out1 (dead after k_elu1) ---
    char*  o1b   = (char*)out1;
    float* out2  = (float*)(o1b);                          // NN*32*4 = 12.8MB (zeroed by memset2)
    float* z2    = (float*)(o1b + 12800000);               // NN*4    = 0.4MB  (zeroed by memset2)
    float* h2a   = (float*)(o1b + 13200128);               // NN*32*4
    float* al_s2 = (float*)(o1b + 26000384);               // NN*4
    float* al_d2 = (float*)(o1b + 26400512);               // NN*4

    const int TB = 256;
    hipMemsetAsync(d_ws, 0, zero_bytes, stream);

    k_flag<<<NN * 128 / TB, TB, 0, stream>>>((const u16*)x, flag);
    k_prep<<<NE * 16 / TB, TB, 0, stream>>>(ei, eattr, flag, deg, attr_sum);
    k_q<<<1, 64, 0, stream>>>(W1e, a1e, W2e, a2e, flag, q1, q2);
    k_gemm1<<<(NN + 63) / 64, TB, 0, stream>>>(x, W1, flag, h1);
    k_al1<<<NN * 128 / TB, TB, 0, stream>>>(h1, a1s, a1d, flag, al_s1, al_d1);
    k_edge_z1<<<NE2 * 16 / TB, TB, 0, stream>>>(ei, eattr, flag, attr_sum, deg, q1, al_s1, al_d1, z1);
    k_edge_agg1<<<NE2 / 4, TB, 0, stream>>>(ei, eattr, flag, attr_sum, deg, q1, al_s1, al_d1, z1, h1, out1);
    k_elu1<<<NN * 128 / TB, TB, 0, stream>>>(out1, b1, flag, h1);
    // out1 now dead; zero the out2+z2 sub-region for layer 2
    hipMemsetAsync(o1b, 0, 13200128, stream);
    k_gemm2<<<(NN + 63) / 64, TB, 0, stream>>>(h1, W2, flag, h2a);
    k_al2<<<NN * 32 / TB, TB, 0, stream>>>(h2a, a2s, a2d, flag, al_s2, al_d2);
    k_edge_z2<<<NE2 * 16 / TB, TB, 0, stream>>>(ei, eattr, flag, attr_sum, deg, q2, al_s2, al_d2, z2);
    k_edge_agg2<<<NE2 / 8, TB, 0, stream>>>(ei, eattr, flag, attr_sum, deg, q2, al_s2, al_d2, z2, h2a, out2, dout);
    k_final<<<NN * 32 / TB, TB, 0, stream>>>(out2, b2, flag, dout);
    k_eidx<<<(2 * NE2 + TB - 1) / TB, TB, 0, stream>>>(ei, dout);
}

// Round 4
// 1005.127 us; speedup vs baseline: 2.4661x; 2.4661x over previous
//
#include <hip/hip_runtime.h>

#define NN 100000
#define NE 1600000
#define NE2 1700000
#define OUT_EI 3200000
#define OUT_AL 6600000
#define SLOPE 0.2f
#define NB_SCAN 391   // ceil(NN/256)

typedef unsigned short u16;
typedef unsigned int u32;
typedef __bf16 bf16x8 __attribute__((ext_vector_type(8)));
typedef float f32x4 __attribute__((ext_vector_type(4)));

__device__ __forceinline__ float bf2f(u16 u){ return __uint_as_float(((u32)u) << 16); }
__device__ __forceinline__ u16 f2bf(float f){
    u32 x = __float_as_uint(f);
    x += 0x7FFFu + ((x >> 16) & 1u);   // round-to-nearest-even
    return (u16)(x >> 16);
}
__device__ __forceinline__ float eluf(float v){ return v > 0.f ? v : (expf(v) - 1.f); }
__device__ __forceinline__ float lreluf(float v){ return v > 0.f ? v : SLOPE * v; }

// ================= CSR build =================
__global__ __launch_bounds__(256) void k_hist(const int* __restrict__ ei, int* __restrict__ deg){
    int e = blockIdx.x * 256 + threadIdx.x;          // NE exact
    atomicAdd(&deg[ei[NE + e]], 1);
}

__global__ __launch_bounds__(256) void k_scan_blk(const int* __restrict__ deg, int* __restrict__ part,
                                                  int* __restrict__ bsum){
    __shared__ int s[256];
    int t = threadIdx.x;
    int i = blockIdx.x * 256 + t;
    int v = (i < NN) ? deg[i] : 0;
    s[t] = v; __syncthreads();
    #pragma unroll
    for (int d = 1; d < 256; d <<= 1){
        int x = (t >= d) ? s[t - d] : 0;
        __syncthreads();
        s[t] += x;
        __syncthreads();
    }
    if (i < NN) part[i] = s[t] - v;                  // exclusive within block
    if (t == 255) bsum[blockIdx.x] = s[255];
}

__global__ void k_scan_top(int* __restrict__ bsum){
    __shared__ int s[512];
    int t = threadIdx.x;                             // 512 threads
    int v = (t < NB_SCAN) ? bsum[t] : 0;
    s[t] = v; __syncthreads();
    #pragma unroll
    for (int d = 1; d < 512; d <<= 1){
        int x = (t >= d) ? s[t - d] : 0;
        __syncthreads();
        s[t] += x;
        __syncthreads();
    }
    bsum[t] = s[t] - v;                              // exclusive
}

__global__ __launch_bounds__(256) void k_scan_add(const int* __restrict__ part, const int* __restrict__ bsum,
                                                  int* __restrict__ offsets, int* __restrict__ cursor,
                                                  int* __restrict__ perm){
    int i = blockIdx.x * 256 + threadIdx.x;
    if (i >= NN) return;
    int base = part[i] + bsum[i >> 8] + i;           // +i: one self-loop slot per preceding node
    offsets[i] = base;
    cursor[i]  = base + 1;                           // real edges start after self-loop slot
    perm[base] = NE + i;                             // self-loop edge id
    if (i == 0) offsets[NN] = NE + NN;
}

__global__ __launch_bounds__(256) void k_scatter(const int* __restrict__ ei, int* __restrict__ cursor,
                                                 int* __restrict__ perm){
    int e = blockIdx.x * 256 + threadIdx.x;          // NE exact
    int dst = ei[NE + e];
    int pos = atomicAdd(&cursor[dst], 1);
    perm[pos] = e;
}

// ================= small precomputes =================
// q1[k*4+h] = sum_c W1e[k,h*32+c]*a1e[h,c]; q2[k] = sum_c W2e[k,c]*a2e[c]
__global__ void k_q(const float* __restrict__ W1e, const float* __restrict__ a1e,
                    const float* __restrict__ W2e, const float* __restrict__ a2e,
                    float* __restrict__ q1, float* __restrict__ q2){
    int t = threadIdx.x;           // 64 threads
    int k = t >> 2, h = t & 3;
    float s = 0.f;
    for (int c = 0; c < 32; c++) s += W1e[k * 128 + h * 32 + c] * a1e[h * 32 + c];
    q1[t] = s;
    if (t < 16){
        float s2 = 0.f;
        for (int c = 0; c < 32; c++) s2 += W2e[t * 32 + c] * a2e[c];
        q2[t] = s2;
    }
}

// per-edge logit contributions: ale1[e,h] = attr[e,:]·q1[:,h], ale2[e] = attr[e,:]·q2  (bf16 store)
__global__ __launch_bounds__(256) void k_ale(const float* __restrict__ eattr,
                                             const float* __restrict__ q1, const float* __restrict__ q2,
                                             u16* __restrict__ ale1, u16* __restrict__ ale2){
    __shared__ float sq1[64], sq2[16];
    int t = threadIdx.x;
    if (t < 64) sq1[t] = q1[t];
    if (t < 16) sq2[t] = q2[t];
    __syncthreads();
    int gt = blockIdx.x * 256 + t;                   // NE*4 exact
    int e = gt >> 2, part = gt & 3;
    f32x4 av = ((const f32x4*)eattr)[(size_t)e * 4 + part];
    int j0 = part * 4;
    float p0 = 0, p1 = 0, p2 = 0, p3 = 0, p4 = 0;
    #pragma unroll
    for (int k = 0; k < 4; k++){
        float a = av[k]; int j = j0 + k;
        p0 += a * sq1[j * 4 + 0]; p1 += a * sq1[j * 4 + 1];
        p2 += a * sq1[j * 4 + 2]; p3 += a * sq1[j * 4 + 3];
        p4 += a * sq2[j];
    }
    #pragma unroll
    for (int m = 1; m < 4; m <<= 1){
        p0 += __shfl_xor(p0, m); p1 += __shfl_xor(p1, m);
        p2 += __shfl_xor(p2, m); p3 += __shfl_xor(p3, m); p4 += __shfl_xor(p4, m);
    }
    if (part == 0){
        ushort4 w; w.x = f2bf(p0); w.y = f2bf(p1); w.z = f2bf(p2); w.w = f2bf(p3);
        ((ushort4*)ale1)[e] = w;
        ale2[e] = f2bf(p4);
    }
}

// ================= GEMMs =================
// h1[N,128] = x[N,128] @ W1[128,128] -> bf16 (MFMA 16x16x32)
__global__ __launch_bounds__(256) void k_gemm1(const float* __restrict__ x, const float* __restrict__ W,
                                               u16* __restrict__ h1){
    __shared__ __align__(16) u16 sW[128 * 136];      // transposed: sW[col*136+k]
    int t = threadIdx.x;
    for (int i = t; i < 128 * 128; i += 256){
        int k = i >> 7, c = i & 127;
        sW[c * 136 + k] = f2bf(W[i]);
    }
    __syncthreads();
    int lane = t & 63, wave = t >> 6;
    int quad = lane >> 4, m16 = lane & 15;
    int rowA = blockIdx.x * 64 + wave * 16 + m16;
    bf16x8 afr[4];
    if (rowA < NN){
        const float* xr = x + (size_t)rowA * 128 + quad * 8;
        #pragma unroll
        for (int kk = 0; kk < 4; kk++)
            #pragma unroll
            for (int i = 0; i < 8; i++) afr[kk][i] = (__bf16)xr[kk * 32 + i];
    } else {
        #pragma unroll
        for (int kk = 0; kk < 4; kk++)
            #pragma unroll
            for (int i = 0; i < 8; i++) afr[kk][i] = (__bf16)0.f;
    }
    int rowbase = blockIdx.x * 64 + wave * 16 + quad * 4;
    #pragma unroll
    for (int nt = 0; nt < 8; nt++){
        f32x4 acc = (f32x4){0.f, 0.f, 0.f, 0.f};
        const u16* wp = &sW[(nt * 16 + m16) * 136 + quad * 8];
        #pragma unroll
        for (int kk = 0; kk < 4; kk++){
            bf16x8 bfr = *(const bf16x8*)(wp + kk * 32);
            acc = __builtin_amdgcn_mfma_f32_16x16x32_bf16(afr[kk], bfr, acc, 0, 0, 0);
        }
        int col = nt * 16 + m16;
        #pragma unroll
        for (int r = 0; r < 4; r++){
            int row = rowbase + r;
            if (row < NN) h1[(size_t)row * 128 + col] = f2bf(acc[r]);
        }
    }
}

// h2a[N,32] = h1b[N,128] @ W2[128,32] -> f32
__global__ __launch_bounds__(256) void k_gemm2(const u16* __restrict__ hin, const float* __restrict__ W,
                                               float* __restrict__ h2a){
    __shared__ __align__(16) u16 sW[32 * 136];
    int t = threadIdx.x;
    for (int i = t; i < 128 * 32; i += 256){
        int k = i >> 5, c = i & 31;
        sW[c * 136 + k] = f2bf(W[i]);
    }
    __syncthreads();
    int lane = t & 63, wave = t >> 6;
    int quad = lane >> 4, m16 = lane & 15;
    int rowA = blockIdx.x * 64 + wave * 16 + m16;
    bf16x8 afr[4];
    if (rowA < NN){
        const u16* xr = hin + (size_t)rowA * 128 + quad * 8;
        #pragma unroll
        for (int kk = 0; kk < 4; kk++) afr[kk] = *(const bf16x8*)(xr + kk * 32);
    } else {
        #pragma unroll
        for (int kk = 0; kk < 4; kk++)
            #pragma unroll
            for (int i = 0; i < 8; i++) afr[kk][i] = (__bf16)0.f;
    }
    int rowbase = blockIdx.x * 64 + wave * 16 + quad * 4;
    #pragma unroll
    for (int nt = 0; nt < 2; nt++){
        f32x4 acc = (f32x4){0.f, 0.f, 0.f, 0.f};
        const u16* wp = &sW[(nt * 16 + m16) * 136 + quad * 8];
        #pragma unroll
        for (int kk = 0; kk < 4; kk++){
            bf16x8 bfr = *(const bf16x8*)(wp + kk * 32);
            acc = __builtin_amdgcn_mfma_f32_16x16x32_bf16(afr[kk], bfr, acc, 0, 0, 0);
        }
        int col = nt * 16 + m16;
        #pragma unroll
        for (int r = 0; r < 4; r++){
            int row = rowbase + r;
            if (row < NN) h2a[(size_t)row * 32 + col] = acc[r];
        }
    }
}

// ================= per-node logits =================
__global__ __launch_bounds__(256) void k_al1(const u16* __restrict__ h1, const float* __restrict__ a1s,
                                             const float* __restrict__ a1d,
                                             float* __restrict__ al_s, float* __restrict__ al_d){
    int idx = blockIdx.x * 256 + threadIdx.x;   // NN*128 exact
    int j = idx & 127;
    float v = bf2f(h1[idx]);
    float vs = v * a1s[j];
    float vd = v * a1d[j];
    #pragma unroll
    for (int m = 1; m < 32; m <<= 1){ vs += __shfl_xor(vs, m); vd += __shfl_xor(vd, m); }
    if ((threadIdx.x & 31) == 0){
        int n = idx >> 7, h = j >> 5;
        al_s[n * 4 + h] = vs;
        al_d[n * 4 + h] = vd;
    }
}

__global__ __launch_bounds__(256) void k_al2(const float* __restrict__ h2a, const float* __restrict__ a2s,
                                             const float* __restrict__ a2d,
                                             float* __restrict__ al_s, float* __restrict__ al_d){
    int idx = blockIdx.x * 256 + threadIdx.x;   // NN*32 exact
    int c = idx & 31;
    float v = h2a[idx];
    float vs = v * a2s[c];
    float vd = v * a2d[c];
    #pragma unroll
    for (int m = 1; m < 32; m <<= 1){ vs += __shfl_xor(vs, m); vd += __shfl_xor(vd, m); }
    if ((threadIdx.x & 31) == 0){
        int n = idx >> 5;
        al_s[n] = vs;
        al_d[n] = vd;
    }
}

// ================= layer 1: per-node softmax + aggregate (wave per node) =================
__global__ __launch_bounds__(256) void k_node1(const int* __restrict__ ei, const int* __restrict__ perm,
                                               const int* __restrict__ offsets,
                                               const u16* __restrict__ ale1,
                                               const float* __restrict__ al_s, const float* __restrict__ al_d,
                                               const u16* __restrict__ h1, const float* __restrict__ b1,
                                               u16* __restrict__ h1b){
    int wave = threadIdx.x >> 6, lane = threadIdx.x & 63;
    int n = blockIdx.x * 4 + wave;               // 25000*4 = NN exact
    int start = offsets[n], end = offsets[n + 1];
    int degr = end - start - 1;
    f32x4 ald  = ((const f32x4*)al_d)[n];
    f32x4 alsn = ((const f32x4*)al_s)[n];
    float z[4] = {0.f, 0.f, 0.f, 0.f}, sa[4] = {0.f, 0.f, 0.f, 0.f};
    for (int i = start + 1 + lane; i < end; i += 64){
        int e = perm[i]; int src = ei[e];
        ushort4 av = ((const ushort4*)ale1)[e];
        f32x4 als = ((const f32x4*)al_s)[src];
        float a0 = bf2f(av.x), a1 = bf2f(av.y), a2 = bf2f(av.z), a3 = bf2f(av.w);
        z[0] += expf(lreluf(als[0] + ald[0] + a0)); sa[0] += a0;
        z[1] += expf(lreluf(als[1] + ald[1] + a1)); sa[1] += a1;
        z[2] += expf(lreluf(als[2] + ald[2] + a2)); sa[2] += a2;
        z[3] += expf(lreluf(als[3] + ald[3] + a3)); sa[3] += a3;
    }
    #pragma unroll
    for (int h = 0; h < 4; h++){
        #pragma unroll
        for (int m = 1; m < 64; m <<= 1){ z[h] += __shfl_xor(z[h], m); sa[h] += __shfl_xor(sa[h], m); }
    }
    float inv_deg = 1.f / fmaxf((float)degr, 1.f);
    float mal[4];
    #pragma unroll
    for (int h = 0; h < 4; h++){
        mal[h] = sa[h] * inv_deg;
        z[h] += expf(lreluf(alsn[h] + ald[h] + mal[h]));
    }
    int hq = lane >> 4;
    float aldh = ald[hq], zh = z[hq], malh = mal[hq];
    float acc0 = 0.f, acc1 = 0.f;
    const u32* h1u = (const u32*)h1;
    for (int i = start; i < end; i++){
        int src; float ale;
        if (i == start){ src = n; ale = malh; }
        else { int e = perm[i]; src = ei[e]; ale = bf2f(ale1[e * 4 + hq]); }
        float alpha = expf(lreluf(al_s[src * 4 + hq] + aldh + ale)) / zh;
        u32 hv = h1u[(size_t)src * 64 + lane];
        acc0 += alpha * bf2f((u16)(hv & 0xFFFFu));
        acc1 += alpha * bf2f((u16)(hv >> 16));
    }
    float v0 = eluf(acc0 + b1[lane * 2]);
    float v1 = eluf(acc1 + b1[lane * 2 + 1]);
    ((u32*)h1b)[(size_t)n * 64 + lane] = (u32)f2bf(v0) | ((u32)f2bf(v1) << 16);
}

// ================= layer 2: per-node softmax + aggregate + outputs =================
__global__ __launch_bounds__(256) void k_node2(const int* __restrict__ ei, const int* __restrict__ perm,
                                               const int* __restrict__ offsets,
                                               const u16* __restrict__ ale2,
                                               const float* __restrict__ al_s, const float* __restrict__ al_d,
                                               const float* __restrict__ h2a, const float* __restrict__ b2,
                                               float* __restrict__ dout){
    int wave = threadIdx.x >> 6, lane = threadIdx.x & 63;
    int n = blockIdx.x * 4 + wave;
    int start = offsets[n], end = offsets[n + 1];
    int degr = end - start - 1;
    float aldn = al_d[n];
    float z = 0.f, sa = 0.f;
    for (int i = start + 1 + lane; i < end; i += 64){
        int e = perm[i]; int src = ei[e];
        float a = bf2f(ale2[e]);
        z += expf(lreluf(al_s[src] + aldn + a));
        sa += a;
    }
    #pragma unroll
    for (int m = 1; m < 64; m <<= 1){ z += __shfl_xor(z, m); sa += __shfl_xor(sa, m); }
    float mal = sa / fmaxf((float)degr, 1.f);
    z += expf(lreluf(al_s[n] + aldn + mal));
    int half = lane >> 5, c = lane & 31;
    float acc = 0.f;
    for (int i = start + half; i < end; i += 2){
        int src, eo; float ale;
        if (i == start){ src = n; ale = mal; eo = NE + n; }
        else { int e = perm[i]; src = ei[e]; ale = bf2f(ale2[e]); eo = e; }
        float alpha = expf(lreluf(al_s[src] + aldn + ale)) / z;
        acc += alpha * h2a[(size_t)src * 32 + c];
        if (c == 0) dout[OUT_AL + eo] = alpha;
    }
    acc += __shfl_xor(acc, 32);
    if (lane < 32) dout[(size_t)n * 32 + c] = eluf(acc + b2[c]);
}

// ================= edge_index_sl output (f32 values) =================
__global__ __launch_bounds__(256) void k_eidx(const int* __restrict__ ei, float* __restrict__ dout){
    int i = blockIdx.x * 256 + threadIdx.x;
    if (i >= 2 * NE2) return;
    int val;
    if (i < NE2) val = (i < NE) ? ei[i] : (i - NE);
    else { int e = i - NE2; val = (e < NE) ? ei[NE + e] : (e - NE); }
    dout[OUT_EI + i] = (float)val;
}

extern "C" void kernel_launch(void* const* d_in, const int* in_sizes, int n_in,
                              void* d_out, int out_size, void* d_ws, size_t ws_size,
                              hipStream_t stream) {
    const float* x     = (const float*)d_in[0];
    const int*   ei    = (const int*)d_in[1];
    const float* eattr = (const float*)d_in[2];
    const float* W1    = (const float*)d_in[3];
    const float* W1e   = (const float*)d_in[4];
    const float* a1s   = (const float*)d_in[5];
    const float* a1d   = (const float*)d_in[6];
    const float* a1e   = (const float*)d_in[7];
    const float* b1    = (const float*)d_in[8];
    const float* W2    = (const float*)d_in[9];
    const float* W2e   = (const float*)d_in[10];
    const float* a2s   = (const float*)d_in[11];
    const float* a2d   = (const float*)d_in[12];
    const float* a2e   = (const float*)d_in[13];
    const float* b2    = (const float*)d_in[14];
    float* dout = (float*)d_out;

    char* ws = (char*)d_ws;
    size_t off = 0;
    auto alloc = [&](size_t bytes) -> void* {
        void* p = ws + off;
        off += (bytes + 255) & ~(size_t)255;
        return p;
    };
    // --- zero-initialized: deg only ---
    int* deg = (int*)alloc((size_t)NN * 4);
    size_t zero_bytes = off;
    // --- rest fully written before read ---
    int*   part    = (int*)alloc((size_t)NN * 4);
    int*   bsum    = (int*)alloc(512 * 4);
    int*   offsets = (int*)alloc((size_t)(NN + 1) * 4);
    int*   cursor  = (int*)alloc((size_t)NN * 4);
    int*   perm    = (int*)alloc((size_t)NE2 * 4);
    float* q1      = (float*)alloc(64 * 4);
    float* q2      = (float*)alloc(16 * 4);
    u16*   ale1    = (u16*)alloc((size_t)NE * 4 * 2);
    u16*   ale2    = (u16*)alloc((size_t)NE * 2);
    float* al_s1   = (float*)alloc((size_t)NN * 4 * 4);
    float* al_d1   = (float*)alloc((size_t)NN * 4 * 4);
    u16*   h1      = (u16*)alloc((size_t)NN * 128 * 2);   // dead after k_node1
    u16*   h1b     = (u16*)alloc((size_t)NN * 128 * 2);
    // layer-2 buffers aliased into h1's region (25.6 MB; need 13.6 MB)
    char*  h1r     = (char*)h1;
    float* h2a     = (float*)(h1r);                        // NN*32*4 = 12.8 MB
    float* al_s2   = (float*)(h1r + 12800000);             // NN*4
    float* al_d2   = (float*)(h1r + 13200128);             // NN*4

    const int TB = 256;
    hipMemsetAsync(d_ws, 0, zero_bytes, stream);

    // CSR build
    k_hist<<<NE / TB, TB, 0, stream>>>(ei, deg);
    k_scan_blk<<<NB_SCAN, TB, 0, stream>>>(deg, part, bsum);
    k_scan_top<<<1, 512, 0, stream>>>(bsum);
    k_scan_add<<<NB_SCAN, TB, 0, stream>>>(part, bsum, offsets, cursor, perm);
    k_scatter<<<NE / TB, TB, 0, stream>>>(ei, cursor, perm);
    // precomputes
    k_q<<<1, 64, 0, stream>>>(W1e, a1e, W2e, a2e, q1, q2);
    k_ale<<<NE * 4 / TB, TB, 0, stream>>>(eattr, q1, q2, ale1, ale2);
    // layer 1
    k_gemm1<<<(NN + 63) / 64, TB, 0, stream>>>(x, W1, h1);
    k_al1<<<NN * 128 / TB, TB, 0, stream>>>(h1, a1s, a1d, al_s1, al_d1);
    k_node1<<<NN / 4, TB, 0, stream>>>(ei, perm, offsets, ale1, al_s1, al_d1, h1, b1, h1b);
    // layer 2 (h1 region reused as h2a/al2 from here)
    k_gemm2<<<(NN + 63) / 64, TB, 0, stream>>>(h1b, W2, h2a);
    k_al2<<<NN * 32 / TB, TB, 0, stream>>>(h2a, a2s, a2d, al_s2, al_d2);
    k_node2<<<NN / 4, TB, 0, stream>>>(ei, perm, offsets, ale2, al_s2, al_d2, h2a, b2, dout);
    // edge index output
    k_eidx<<<(2 * NE2 + TB - 1) / TB, TB, 0, stream>>>(ei, dout);
}

// Round 5
// 822.027 us; speedup vs baseline: 3.0154x; 1.2227x over previous
//
#include <hip/hip_runtime.h>

#define NN 100000
#define NE 1600000
#define NE2 1700000
#define OUT_EI 3200000
#define OUT_AL 6600000
#define SLOPE 0.2f
#define NB_SCAN 391   // ceil(NN/256)

typedef unsigned short u16;
typedef unsigned int u32;
typedef __bf16 bf16x8 __attribute__((ext_vector_type(8)));
typedef float f32x4 __attribute__((ext_vector_type(4)));

__device__ __forceinline__ float bf2f(u16 u){ return __uint_as_float(((u32)u) << 16); }
__device__ __forceinline__ u16 f2bf(float f){
    u32 x = __float_as_uint(f);
    x += 0x7FFFu + ((x >> 16) & 1u);   // round-to-nearest-even
    return (u16)(x >> 16);
}
__device__ __forceinline__ float eluf(float v){ return v > 0.f ? v : (__expf(v) - 1.f); }
__device__ __forceinline__ float lreluf(float v){ return fmaxf(v, SLOPE * v); }

// ================= CSR build =================
__global__ __launch_bounds__(256) void k_hist(const int* __restrict__ ei, int* __restrict__ deg){
    int e = blockIdx.x * 256 + threadIdx.x;          // NE exact
    atomicAdd(&deg[ei[NE + e]], 1);
}

__global__ __launch_bounds__(256) void k_scan_blk(const int* __restrict__ deg, int* __restrict__ part,
                                                  int* __restrict__ bsum){
    __shared__ int s[256];
    int t = threadIdx.x;
    int i = blockIdx.x * 256 + t;
    int v = (i < NN) ? deg[i] : 0;
    s[t] = v; __syncthreads();
    #pragma unroll
    for (int d = 1; d < 256; d <<= 1){
        int x = (t >= d) ? s[t - d] : 0;
        __syncthreads();
        s[t] += x;
        __syncthreads();
    }
    if (i < NN) part[i] = s[t] - v;                  // exclusive within block
    if (t == 255) bsum[blockIdx.x] = s[255];
}

__global__ void k_scan_top(int* __restrict__ bsum){
    __shared__ int s[512];
    int t = threadIdx.x;                             // 512 threads
    int v = (t < NB_SCAN) ? bsum[t] : 0;
    s[t] = v; __syncthreads();
    #pragma unroll
    for (int d = 1; d < 512; d <<= 1){
        int x = (t >= d) ? s[t - d] : 0;
        __syncthreads();
        s[t] += x;
        __syncthreads();
    }
    bsum[t] = s[t] - v;                              // exclusive
}

__global__ __launch_bounds__(256) void k_scan_add(const int* __restrict__ part, const int* __restrict__ bsum,
                                                  int* __restrict__ offsets, int* __restrict__ cursor){
    int i = blockIdx.x * 256 + threadIdx.x;
    if (i >= NN) return;
    int base = part[i] + bsum[i >> 8] + i;           // +i: one self-loop slot per preceding node
    offsets[i] = base;
    cursor[i]  = base + 1;                           // real edges start after self-loop slot
    if (i == 0) offsets[NN] = NE + NN;
}

// scatter edges into CSR slots, materializing slot-ordered src / ale copies
__global__ __launch_bounds__(256) void k_scatter(const int* __restrict__ ei,
                                                 const u16* __restrict__ ale1, const u16* __restrict__ ale2,
                                                 int* __restrict__ cursor,
                                                 int* __restrict__ perm, int* __restrict__ src32,
                                                 ushort4* __restrict__ ale1p, u16* __restrict__ ale2p){
    int e = blockIdx.x * 256 + threadIdx.x;          // NE exact
    int src = ei[e];
    int dst = ei[NE + e];
    int pos = atomicAdd(&cursor[dst], 1);
    perm[pos]  = e;
    src32[pos] = src;
    ale1p[pos] = ((const ushort4*)ale1)[e];
    ale2p[pos] = ale2[e];
}

// ================= small precomputes =================
// q1[k*4+h] = sum_c W1e[k,h*32+c]*a1e[h,c]; q2[k] = sum_c W2e[k,c]*a2e[c]
__global__ void k_q(const float* __restrict__ W1e, const float* __restrict__ a1e,
                    const float* __restrict__ W2e, const float* __restrict__ a2e,
                    float* __restrict__ q1, float* __restrict__ q2){
    int t = threadIdx.x;           // 64 threads
    int k = t >> 2, h = t & 3;
    float s = 0.f;
    for (int c = 0; c < 32; c++) s += W1e[k * 128 + h * 32 + c] * a1e[h * 32 + c];
    q1[t] = s;
    if (t < 16){
        float s2 = 0.f;
        for (int c = 0; c < 32; c++) s2 += W2e[t * 32 + c] * a2e[c];
        q2[t] = s2;
    }
}

// per-edge logit contributions: ale1[e,h] = attr[e,:]·q1[:,h], ale2[e] = attr[e,:]·q2  (bf16 store)
__global__ __launch_bounds__(256) void k_ale(const float* __restrict__ eattr,
                                             const float* __restrict__ q1, const float* __restrict__ q2,
                                             u16* __restrict__ ale1, u16* __restrict__ ale2){
    __shared__ float sq1[64], sq2[16];
    int t = threadIdx.x;
    if (t < 64) sq1[t] = q1[t];
    if (t < 16) sq2[t] = q2[t];
    __syncthreads();
    int gt = blockIdx.x * 256 + t;                   // NE*4 exact
    int e = gt >> 2, part = gt & 3;
    f32x4 av = ((const f32x4*)eattr)[(size_t)e * 4 + part];
    int j0 = part * 4;
    float p0 = 0, p1 = 0, p2 = 0, p3 = 0, p4 = 0;
    #pragma unroll
    for (int k = 0; k < 4; k++){
        float a = av[k]; int j = j0 + k;
        p0 += a * sq1[j * 4 + 0]; p1 += a * sq1[j * 4 + 1];
        p2 += a * sq1[j * 4 + 2]; p3 += a * sq1[j * 4 + 3];
        p4 += a * sq2[j];
    }
    #pragma unroll
    for (int m = 1; m < 4; m <<= 1){
        p0 += __shfl_xor(p0, m); p1 += __shfl_xor(p1, m);
        p2 += __shfl_xor(p2, m); p3 += __shfl_xor(p3, m); p4 += __shfl_xor(p4, m);
    }
    if (part == 0){
        ushort4 w; w.x = f2bf(p0); w.y = f2bf(p1); w.z = f2bf(p2); w.w = f2bf(p3);
        ((ushort4*)ale1)[e] = w;
        ale2[e] = f2bf(p4);
    }
}

// ================= GEMMs =================
// h1[N,128] = x[N,128] @ W1[128,128] -> bf16 (MFMA 16x16x32)
__global__ __launch_bounds__(256) void k_gemm1(const float* __restrict__ x, const float* __restrict__ W,
                                               u16* __restrict__ h1){
    __shared__ __align__(16) u16 sW[128 * 136];      // transposed: sW[col*136+k]
    int t = threadIdx.x;
    for (int i = t; i < 128 * 128; i += 256){
        int k = i >> 7, c = i & 127;
        sW[c * 136 + k] = f2bf(W[i]);
    }
    __syncthreads();
    int lane = t & 63, wave = t >> 6;
    int quad = lane >> 4, m16 = lane & 15;
    int rowA = blockIdx.x * 64 + wave * 16 + m16;
    bf16x8 afr[4];
    if (rowA < NN){
        const float* xr = x + (size_t)rowA * 128 + quad * 8;
        #pragma unroll
        for (int kk = 0; kk < 4; kk++)
            #pragma unroll
            for (int i = 0; i < 8; i++) afr[kk][i] = (__bf16)xr[kk * 32 + i];
    } else {
        #pragma unroll
        for (int kk = 0; kk < 4; kk++)
            #pragma unroll
            for (int i = 0; i < 8; i++) afr[kk][i] = (__bf16)0.f;
    }
    int rowbase = blockIdx.x * 64 + wave * 16 + quad * 4;
    #pragma unroll
    for (int nt = 0; nt < 8; nt++){
        f32x4 acc = (f32x4){0.f, 0.f, 0.f, 0.f};
        const u16* wp = &sW[(nt * 16 + m16) * 136 + quad * 8];
        #pragma unroll
        for (int kk = 0; kk < 4; kk++){
            bf16x8 bfr = *(const bf16x8*)(wp + kk * 32);
            acc = __builtin_amdgcn_mfma_f32_16x16x32_bf16(afr[kk], bfr, acc, 0, 0, 0);
        }
        int col = nt * 16 + m16;
        #pragma unroll
        for (int r = 0; r < 4; r++){
            int row = rowbase + r;
            if (row < NN) h1[(size_t)row * 128 + col] = f2bf(acc[r]);
        }
    }
}

// h2a[N,32] = h1b[N,128] @ W2[128,32] -> f32
__global__ __launch_bounds__(256) void k_gemm2(const u16* __restrict__ hin, const float* __restrict__ W,
                                               float* __restrict__ h2a){
    __shared__ __align__(16) u16 sW[32 * 136];
    int t = threadIdx.x;
    for (int i = t; i < 128 * 32; i += 256){
        int k = i >> 5, c = i & 31;
        sW[c * 136 + k] = f2bf(W[i]);
    }
    __syncthreads();
    int lane = t & 63, wave = t >> 6;
    int quad = lane >> 4, m16 = lane & 15;
    int rowA = blockIdx.x * 64 + wave * 16 + m16;
    bf16x8 afr[4];
    if (rowA < NN){
        const u16* xr = hin + (size_t)rowA * 128 + quad * 8;
        #pragma unroll
        for (int kk = 0; kk < 4; kk++) afr[kk] = *(const bf16x8*)(xr + kk * 32);
    } else {
        #pragma unroll
        for (int kk = 0; kk < 4; kk++)
            #pragma unroll
            for (int i = 0; i < 8; i++) afr[kk][i] = (__bf16)0.f;
    }
    int rowbase = blockIdx.x * 64 + wave * 16 + quad * 4;
    #pragma unroll
    for (int nt = 0; nt < 2; nt++){
        f32x4 acc = (f32x4){0.f, 0.f, 0.f, 0.f};
        const u16* wp = &sW[(nt * 16 + m16) * 136 + quad * 8];
        #pragma unroll
        for (int kk = 0; kk < 4; kk++){
            bf16x8 bfr = *(const bf16x8*)(wp + kk * 32);
            acc = __builtin_amdgcn_mfma_f32_16x16x32_bf16(afr[kk], bfr, acc, 0, 0, 0);
        }
        int col = nt * 16 + m16;
        #pragma unroll
        for (int r = 0; r < 4; r++){
            int row = rowbase + r;
            if (row < NN) h2a[(size_t)row * 32 + col] = acc[r];
        }
    }
}

// ================= per-node logits =================
__global__ __launch_bounds__(256) void k_al1(const u16* __restrict__ h1, const float* __restrict__ a1s,
                                             const float* __restrict__ a1d,
                                             float* __restrict__ al_s, float* __restrict__ al_d){
    int idx = blockIdx.x * 256 + threadIdx.x;   // NN*128 exact
    int j = idx & 127;
    float v = bf2f(h1[idx]);
    float vs = v * a1s[j];
    float vd = v * a1d[j];
    #pragma unroll
    for (int m = 1; m < 32; m <<= 1){ vs += __shfl_xor(vs, m); vd += __shfl_xor(vd, m); }
    if ((threadIdx.x & 31) == 0){
        int n = idx >> 7, h = j >> 5;
        al_s[n * 4 + h] = vs;
        al_d[n * 4 + h] = vd;
    }
}

__global__ __launch_bounds__(256) void k_al2(const float* __restrict__ h2a, const float* __restrict__ a2s,
                                             const float* __restrict__ a2d,
                                             float* __restrict__ al_s, float* __restrict__ al_d){
    int idx = blockIdx.x * 256 + threadIdx.x;   // NN*32 exact
    int c = idx & 31;
    float v = h2a[idx];
    float vs = v * a2s[c];
    float vd = v * a2d[c];
    #pragma unroll
    for (int m = 1; m < 32; m <<= 1){ vs += __shfl_xor(vs, m); vd += __shfl_xor(vd, m); }
    if ((threadIdx.x & 31) == 0){
        int n = idx >> 5;
        al_s[n] = vs;
        al_d[n] = vd;
    }
}

// ================= layer 1: per-node softmax + aggregate (wave per node) =================
__global__ __launch_bounds__(256) void k_node1(const int* __restrict__ src32, const ushort4* __restrict__ ale1p,
                                               const int* __restrict__ offsets,
                                               const float* __restrict__ al_s, const float* __restrict__ al_d,
                                               const u16* __restrict__ h1, const float* __restrict__ b1,
                                               u16* __restrict__ h1b, ushort4* __restrict__ pb1){
    int wave = threadIdx.x >> 6, lane = threadIdx.x & 63;
    int n = blockIdx.x * 4 + wave;               // 25000*4 = NN exact
    int start = offsets[n], end = offsets[n + 1];
    int degr = end - start - 1;
    f32x4 ald  = ((const f32x4*)al_d)[n];
    f32x4 alsn = ((const f32x4*)al_s)[n];
    float z0 = 0, z1 = 0, z2 = 0, z3 = 0, s0 = 0, s1 = 0, s2 = 0, s3 = 0;
    // phase A: numerators p_e (stored bf16) + denominator z + edge-logit mean (lane-parallel)
    for (int i = start + 1 + lane; i < end; i += 64){
        int src = src32[i];
        ushort4 av = ale1p[i];
        f32x4 als = ((const f32x4*)al_s)[src];
        float a0 = bf2f(av.x), a1 = bf2f(av.y), a2 = bf2f(av.z), a3 = bf2f(av.w);
        float e0 = __expf(lreluf(als[0] + ald[0] + a0));
        float e1 = __expf(lreluf(als[1] + ald[1] + a1));
        float e2 = __expf(lreluf(als[2] + ald[2] + a2));
        float e3 = __expf(lreluf(als[3] + ald[3] + a3));
        z0 += e0; z1 += e1; z2 += e2; z3 += e3;
        s0 += a0; s1 += a1; s2 += a2; s3 += a3;
        ushort4 w; w.x = f2bf(e0); w.y = f2bf(e1); w.z = f2bf(e2); w.w = f2bf(e3);
        pb1[i] = w;
    }
    #pragma unroll
    for (int m = 1; m < 64; m <<= 1){
        z0 += __shfl_xor(z0, m); z1 += __shfl_xor(z1, m); z2 += __shfl_xor(z2, m); z3 += __shfl_xor(z3, m);
        s0 += __shfl_xor(s0, m); s1 += __shfl_xor(s1, m); s2 += __shfl_xor(s2, m); s3 += __shfl_xor(s3, m);
    }
    float inv_deg = 1.f / fmaxf((float)degr, 1.f);
    float p0 = __expf(lreluf(alsn[0] + ald[0] + s0 * inv_deg)); z0 += p0;
    float p1 = __expf(lreluf(alsn[1] + ald[1] + s1 * inv_deg)); z1 += p1;
    float p2 = __expf(lreluf(alsn[2] + ald[2] + s2 * inv_deg)); z2 += p2;
    float p3 = __expf(lreluf(alsn[3] + ald[3] + s3 * inv_deg)); z3 += p3;
    int hq = lane >> 4;
    float rz = 1.f / ((hq == 0) ? z0 : (hq == 1) ? z1 : (hq == 2) ? z2 : z3);
    float ps = (hq == 0) ? p0 : (hq == 1) ? p1 : (hq == 2) ? p2 : p3;
    // phase B: aggregate (p broadcast from L1, h1 row gather; rz factored out)
    const u32* h1u = (const u32*)h1;
    const u16* pbu = (const u16*)pb1;
    u32 hv = h1u[(size_t)n * 64 + lane];
    float acc0 = ps * bf2f((u16)(hv & 0xFFFFu));
    float acc1 = ps * bf2f((u16)(hv >> 16));
    for (int i = start + 1; i < end; i++){
        int src = src32[i];
        float p = bf2f(pbu[(size_t)i * 4 + hq]);
        u32 v = h1u[(size_t)src * 64 + lane];
        acc0 += p * bf2f((u16)(v & 0xFFFFu));
        acc1 += p * bf2f((u16)(v >> 16));
    }
    float v0 = eluf(acc0 * rz + b1[lane * 2]);
    float v1 = eluf(acc1 * rz + b1[lane * 2 + 1]);
    ((u32*)h1b)[(size_t)n * 64 + lane] = (u32)f2bf(v0) | ((u32)f2bf(v1) << 16);
}

// ================= layer 2: per-node softmax + aggregate + outputs =================
__global__ __launch_bounds__(256) void k_node2(const int* __restrict__ src32, const u16* __restrict__ ale2p,
                                               const int* __restrict__ perm, const int* __restrict__ offsets,
                                               const float* __restrict__ al_s, const float* __restrict__ al_d,
                                               const float* __restrict__ h2a, const float* __restrict__ b2,
                                               float* __restrict__ dout, u16* __restrict__ pb2){
    int wave = threadIdx.x >> 6, lane = threadIdx.x & 63;
    int n = blockIdx.x * 4 + wave;
    int start = offsets[n], end = offsets[n + 1];
    int degr = end - start - 1;
    float aldn = al_d[n];
    float z = 0.f, sa = 0.f;
    for (int i = start + 1 + lane; i < end; i += 64){
        int src = src32[i];
        float a = bf2f(ale2p[i]);
        float ev = __expf(lreluf(al_s[src] + aldn + a));
        z += ev; sa += a;
        pb2[i] = f2bf(ev);
    }
    #pragma unroll
    for (int m = 1; m < 64; m <<= 1){ z += __shfl_xor(z, m); sa += __shfl_xor(sa, m); }
    float mal = sa / fmaxf((float)degr, 1.f);
    float pself = __expf(lreluf(al_s[n] + aldn + mal));
    z += pself;
    float rz = 1.f / z;
    int half = lane >> 5, c = lane & 31;
    float acc = 0.f;
    for (int i = start + half; i < end; i += 2){
        float alpha; int src;
        if (i == start){
            alpha = pself * rz; src = n;
            if (c == 0) dout[OUT_AL + NE + n] = alpha;
        } else {
            alpha = bf2f(pb2[i]) * rz; src = src32[i];
            if (c == 0) dout[OUT_AL + perm[i]] = alpha;
        }
        acc += alpha * h2a[(size_t)src * 32 + c];
    }
    acc += __shfl_xor(acc, 32);
    if (lane < 32) dout[(size_t)n * 32 + c] = eluf(acc + b2[c]);
}

// ================= edge_index_sl output (f32 values) =================
__global__ __launch_bounds__(256) void k_eidx(const int* __restrict__ ei, float* __restrict__ dout){
    int i = blockIdx.x * 256 + threadIdx.x;
    if (i >= 2 * NE2) return;
    int val;
    if (i < NE2) val = (i < NE) ? ei[i] : (i - NE);
    else { int e = i - NE2; val = (e < NE) ? ei[NE + e] : (e - NE); }
    dout[OUT_EI + i] = (float)val;
}

extern "C" void kernel_launch(void* const* d_in, const int* in_sizes, int n_in,
                              void* d_out, int out_size, void* d_ws, size_t ws_size,
                              hipStream_t stream) {
    const float* x     = (const float*)d_in[0];
    const int*   ei    = (const int*)d_in[1];
    const float* eattr = (const float*)d_in[2];
    const float* W1    = (const float*)d_in[3];
    const float* W1e   = (const float*)d_in[4];
    const float* a1s   = (const float*)d_in[5];
    const float* a1d   = (const float*)d_in[6];
    const float* a1e   = (const float*)d_in[7];
    const float* b1    = (const float*)d_in[8];
    const float* W2    = (const float*)d_in[9];
    const float* W2e   = (const float*)d_in[10];
    const float* a2s   = (const float*)d_in[11];
    const float* a2d   = (const float*)d_in[12];
    const float* a2e   = (const float*)d_in[13];
    const float* b2    = (const float*)d_in[14];
    float* dout = (float*)d_out;

    char* ws = (char*)d_ws;
    size_t off = 0;
    auto alloc = [&](size_t bytes) -> void* {
        void* p = ws + off;
        off += (bytes + 255) & ~(size_t)255;
        return p;
    };
    // --- zero-initialized: deg only ---
    int* deg = (int*)alloc((size_t)NN * 4);
    size_t zero_bytes = off;
    // --- rest fully written before read ---
    int*     part    = (int*)alloc((size_t)NN * 4);
    int*     bsum    = (int*)alloc(512 * 4);
    int*     offsets = (int*)alloc((size_t)(NN + 1) * 4);
    int*     cursor  = (int*)alloc((size_t)NN * 4);
    int*     perm    = (int*)alloc((size_t)NE2 * 4);
    int*     src32   = (int*)alloc((size_t)NE2 * 4);
    ushort4* ale1p   = (ushort4*)alloc((size_t)NE2 * 8);
    u16*     ale2p   = (u16*)alloc((size_t)NE2 * 2);
    ushort4* pb1     = (ushort4*)alloc((size_t)NE2 * 8);
    float*   q1      = (float*)alloc(64 * 4);
    float*   q2      = (float*)alloc(16 * 4);
    u16*     ale1    = (u16*)alloc((size_t)NE * 4 * 2);   // dead after k_scatter
    u16*     ale2    = (u16*)alloc((size_t)NE * 2);
    float*   al_s1   = (float*)alloc((size_t)NN * 4 * 4);
    float*   al_d1   = (float*)alloc((size_t)NN * 4 * 4);
    u16*     h1      = (u16*)alloc((size_t)NN * 128 * 2); // dead after k_node1
    u16*     h1b     = (u16*)alloc((size_t)NN * 128 * 2);
    // aliases into dead regions
    u16*   pb2   = (u16*)ale1;                            // NE2*2 = 3.4 MB <= 12.8 MB
    char*  h1r   = (char*)h1;
    float* h2a   = (float*)(h1r);                         // NN*32*4 = 12.8 MB
    float* al_s2 = (float*)(h1r + 12800000);              // NN*4
    float* al_d2 = (float*)(h1r + 13200128);              // NN*4

    const int TB = 256;
    hipMemsetAsync(d_ws, 0, zero_bytes, stream);

    // CSR build
    k_hist<<<NE / TB, TB, 0, stream>>>(ei, deg);
    k_scan_blk<<<NB_SCAN, TB, 0, stream>>>(deg, part, bsum);
    k_scan_top<<<1, 512, 0, stream>>>(bsum);
    k_scan_add<<<NB_SCAN, TB, 0, stream>>>(part, bsum, offsets, cursor);
    // precomputes (ale before scatter so scatter can permute them)
    k_q<<<1, 64, 0, stream>>>(W1e, a1e, W2e, a2e, q1, q2);
    k_ale<<<NE * 4 / TB, TB, 0, stream>>>(eattr, q1, q2, ale1, ale2);
    k_scatter<<<NE / TB, TB, 0, stream>>>(ei, ale1, ale2, cursor, perm, src32, ale1p, ale2p);
    // layer 1
    k_gemm1<<<(NN + 63) / 64, TB, 0, stream>>>(x, W1, h1);
    k_al1<<<NN * 128 / TB, TB, 0, stream>>>(h1, a1s, a1d, al_s1, al_d1);
    k_node1<<<NN / 4, TB, 0, stream>>>(src32, ale1p, offsets, al_s1, al_d1, h1, b1, h1b, pb1);
    // layer 2 (h1 region reused as h2a/al2; ale1 region reused as pb2)
    k_gemm2<<<(NN + 63) / 64, TB, 0, stream>>>(h1b, W2, h2a);
    k_al2<<<NN * 32 / TB, TB, 0, stream>>>(h2a, a2s, a2d, al_s2, al_d2);
    k_node2<<<NN / 4, TB, 0, stream>>>(src32, ale2p, perm, offsets, al_s2, al_d2, h2a, b2, dout, pb2);
    // edge index output
    k_eidx<<<(2 * NE2 + TB - 1) / TB, TB, 0, stream>>>(ei, dout);
}

// Round 6
// 745.311 us; speedup vs baseline: 3.3257x; 1.1029x over previous
//
#include <hip/hip_runtime.h>

#define NN 100000
#define NE 1600000
#define NE2 1700000
#define OUT_EI 3200000
#define OUT_AL 6600000
#define SLOPE 0.2f
#define NB_SCAN 391   // ceil(NN/256)

typedef unsigned short u16;
typedef unsigned int u32;
typedef __bf16 bf16x8 __attribute__((ext_vector_type(8)));
typedef float f32x4 __attribute__((ext_vector_type(4)));
typedef u32 u32x4 __attribute__((ext_vector_type(4)));

__device__ __forceinline__ float bf2f(u16 u){ return __uint_as_float(((u32)u) << 16); }
__device__ __forceinline__ u16 f2bf(float f){
    u32 x = __float_as_uint(f);
    x += 0x7FFFu + ((x >> 16) & 1u);   // round-to-nearest-even
    return (u16)(x >> 16);
}
__device__ __forceinline__ float eluf(float v){ return v > 0.f ? v : (__expf(v) - 1.f); }
__device__ __forceinline__ float lreluf(float v){ return fmaxf(v, SLOPE * v); }

// ================= CSR build =================
__global__ __launch_bounds__(256) void k_hist(const int* __restrict__ ei, int* __restrict__ deg){
    int e = blockIdx.x * 256 + threadIdx.x;          // NE exact
    atomicAdd(&deg[ei[NE + e]], 1);
}

__global__ __launch_bounds__(256) void k_scan_blk(const int* __restrict__ deg, int* __restrict__ part,
                                                  int* __restrict__ bsum){
    __shared__ int s[256];
    int t = threadIdx.x;
    int i = blockIdx.x * 256 + t;
    int v = (i < NN) ? deg[i] : 0;
    s[t] = v; __syncthreads();
    #pragma unroll
    for (int d = 1; d < 256; d <<= 1){
        int x = (t >= d) ? s[t - d] : 0;
        __syncthreads();
        s[t] += x;
        __syncthreads();
    }
    if (i < NN) part[i] = s[t] - v;                  // exclusive within block
    if (t == 255) bsum[blockIdx.x] = s[255];
}

__global__ void k_scan_top(int* __restrict__ bsum){
    __shared__ int s[512];
    int t = threadIdx.x;                             // 512 threads
    int v = (t < NB_SCAN) ? bsum[t] : 0;
    s[t] = v; __syncthreads();
    #pragma unroll
    for (int d = 1; d < 512; d <<= 1){
        int x = (t >= d) ? s[t - d] : 0;
        __syncthreads();
        s[t] += x;
        __syncthreads();
    }
    bsum[t] = s[t] - v;                              // exclusive
}

__global__ __launch_bounds__(256) void k_scan_add(const int* __restrict__ part, const int* __restrict__ bsum,
                                                  int* __restrict__ offsets, int* __restrict__ cursor,
                                                  int* __restrict__ perm){
    int i = blockIdx.x * 256 + threadIdx.x;
    if (i >= NN) return;
    int base = part[i] + bsum[i >> 8] + i;           // +i: one self-loop slot per preceding node
    offsets[i] = base;
    cursor[i]  = base + 1;                           // real edges start after self-loop slot
    perm[base] = NE + i;                             // self-loop edge id
    if (i == 0) offsets[NN] = NE + NN;
}

// scatter edge ids only (4B per edge; lines L2-resident since dst-contiguous)
__global__ __launch_bounds__(256) void k_scatter(const int* __restrict__ ei, int* __restrict__ cursor,
                                                 int* __restrict__ perm){
    int e = blockIdx.x * 256 + threadIdx.x;          // NE exact
    int dst = ei[NE + e];
    int pos = atomicAdd(&cursor[dst], 1);
    perm[pos] = e;
}

// flat payload gather: slot-ordered src / ale copies (coalesced writes, cached random reads)
__global__ __launch_bounds__(256) void k_perm(const int* __restrict__ perm, const int* __restrict__ ei,
                                              const u16* __restrict__ ale1, const u16* __restrict__ ale2,
                                              int* __restrict__ src32, ushort4* __restrict__ ale1p,
                                              u16* __restrict__ ale2p){
    int i = blockIdx.x * 256 + threadIdx.x;
    if (i >= NE2) return;
    int e = perm[i];
    if (e >= NE){                                    // self-loop slot (payload never read)
        src32[i] = e - NE;
        ushort4 z4; z4.x = z4.y = z4.z = z4.w = 0;
        ale1p[i] = z4; ale2p[i] = 0;
        return;
    }
    src32[i] = ei[e];
    ale1p[i] = ((const ushort4*)ale1)[e];
    ale2p[i] = ale2[e];
}

// ================= small precomputes =================
__global__ void k_q(const float* __restrict__ W1e, const float* __restrict__ a1e,
                    const float* __restrict__ W2e, const float* __restrict__ a2e,
                    float* __restrict__ q1, float* __restrict__ q2){
    int t = threadIdx.x;           // 64 threads
    int k = t >> 2, h = t & 3;
    float s = 0.f;
    for (int c = 0; c < 32; c++) s += W1e[k * 128 + h * 32 + c] * a1e[h * 32 + c];
    q1[t] = s;
    if (t < 16){
        float s2 = 0.f;
        for (int c = 0; c < 32; c++) s2 += W2e[t * 32 + c] * a2e[c];
        q2[t] = s2;
    }
}

__global__ __launch_bounds__(256) void k_ale(const float* __restrict__ eattr,
                                             const float* __restrict__ q1, const float* __restrict__ q2,
                                             u16* __restrict__ ale1, u16* __restrict__ ale2){
    __shared__ float sq1[64], sq2[16];
    int t = threadIdx.x;
    if (t < 64) sq1[t] = q1[t];
    if (t < 16) sq2[t] = q2[t];
    __syncthreads();
    int gt = blockIdx.x * 256 + t;                   // NE*4 exact
    int e = gt >> 2, part = gt & 3;
    f32x4 av = ((const f32x4*)eattr)[(size_t)e * 4 + part];
    int j0 = part * 4;
    float p0 = 0, p1 = 0, p2 = 0, p3 = 0, p4 = 0;
    #pragma unroll
    for (int k = 0; k < 4; k++){
        float a = av[k]; int j = j0 + k;
        p0 += a * sq1[j * 4 + 0]; p1 += a * sq1[j * 4 + 1];
        p2 += a * sq1[j * 4 + 2]; p3 += a * sq1[j * 4 + 3];
        p4 += a * sq2[j];
    }
    #pragma unroll
    for (int m = 1; m < 4; m <<= 1){
        p0 += __shfl_xor(p0, m); p1 += __shfl_xor(p1, m);
        p2 += __shfl_xor(p2, m); p3 += __shfl_xor(p3, m); p4 += __shfl_xor(p4, m);
    }
    if (part == 0){
        ushort4 w; w.x = f2bf(p0); w.y = f2bf(p1); w.z = f2bf(p2); w.w = f2bf(p3);
        ((ushort4*)ale1)[e] = w;
        ale2[e] = f2bf(p4);
    }
}

// ================= GEMMs =================
__global__ __launch_bounds__(256) void k_gemm1(const float* __restrict__ x, const float* __restrict__ W,
                                               u16* __restrict__ h1){
    __shared__ __align__(16) u16 sW[128 * 136];      // transposed: sW[col*136+k]
    int t = threadIdx.x;
    for (int i = t; i < 128 * 128; i += 256){
        int k = i >> 7, c = i & 127;
        sW[c * 136 + k] = f2bf(W[i]);
    }
    __syncthreads();
    int lane = t & 63, wave = t >> 6;
    int quad = lane >> 4, m16 = lane & 15;
    int rowA = blockIdx.x * 64 + wave * 16 + m16;
    bf16x8 afr[4];
    if (rowA < NN){
        const f32x4* xr = (const f32x4*)(x + (size_t)rowA * 128);
        #pragma unroll
        for (int kk = 0; kk < 4; kk++){
            f32x4 va = xr[kk * 8 + quad * 2];
            f32x4 vb = xr[kk * 8 + quad * 2 + 1];
            #pragma unroll
            for (int i = 0; i < 4; i++){ afr[kk][i] = (__bf16)va[i]; afr[kk][4 + i] = (__bf16)vb[i]; }
        }
    } else {
        #pragma unroll
        for (int kk = 0; kk < 4; kk++)
            #pragma unroll
            for (int i = 0; i < 8; i++) afr[kk][i] = (__bf16)0.f;
    }
    int rowbase = blockIdx.x * 64 + wave * 16 + quad * 4;
    #pragma unroll
    for (int nt = 0; nt < 8; nt++){
        f32x4 acc = (f32x4){0.f, 0.f, 0.f, 0.f};
        const u16* wp = &sW[(nt * 16 + m16) * 136 + quad * 8];
        #pragma unroll
        for (int kk = 0; kk < 4; kk++){
            bf16x8 bfr = *(const bf16x8*)(wp + kk * 32);
            acc = __builtin_amdgcn_mfma_f32_16x16x32_bf16(afr[kk], bfr, acc, 0, 0, 0);
        }
        int col = nt * 16 + m16;
        #pragma unroll
        for (int r = 0; r < 4; r++){
            int row = rowbase + r;
            if (row < NN) h1[(size_t)row * 128 + col] = f2bf(acc[r]);
        }
    }
}

__global__ __launch_bounds__(256) void k_gemm2(const u16* __restrict__ hin, const float* __restrict__ W,
                                               float* __restrict__ h2a){
    __shared__ __align__(16) u16 sW[32 * 136];
    int t = threadIdx.x;
    for (int i = t; i < 128 * 32; i += 256){
        int k = i >> 5, c = i & 31;
        sW[c * 136 + k] = f2bf(W[i]);
    }
    __syncthreads();
    int lane = t & 63, wave = t >> 6;
    int quad = lane >> 4, m16 = lane & 15;
    int rowA = blockIdx.x * 64 + wave * 16 + m16;
    bf16x8 afr[4];
    if (rowA < NN){
        const u16* xr = hin + (size_t)rowA * 128 + quad * 8;
        #pragma unroll
        for (int kk = 0; kk < 4; kk++) afr[kk] = *(const bf16x8*)(xr + kk * 32);
    } else {
        #pragma unroll
        for (int kk = 0; kk < 4; kk++)
            #pragma unroll
            for (int i = 0; i < 8; i++) afr[kk][i] = (__bf16)0.f;
    }
    int rowbase = blockIdx.x * 64 + wave * 16 + quad * 4;
    #pragma unroll
    for (int nt = 0; nt < 2; nt++){
        f32x4 acc = (f32x4){0.f, 0.f, 0.f, 0.f};
        const u16* wp = &sW[(nt * 16 + m16) * 136 + quad * 8];
        #pragma unroll
        for (int kk = 0; kk < 4; kk++){
            bf16x8 bfr = *(const bf16x8*)(wp + kk * 32);
            acc = __builtin_amdgcn_mfma_f32_16x16x32_bf16(afr[kk], bfr, acc, 0, 0, 0);
        }
        int col = nt * 16 + m16;
        #pragma unroll
        for (int r = 0; r < 4; r++){
            int row = rowbase + r;
            if (row < NN) h2a[(size_t)row * 32 + col] = acc[r];
        }
    }
}

// ================= per-node logits =================
__global__ __launch_bounds__(256) void k_al1(const u16* __restrict__ h1, const float* __restrict__ a1s,
                                             const float* __restrict__ a1d,
                                             float* __restrict__ al_s, float* __restrict__ al_d){
    int idx = blockIdx.x * 256 + threadIdx.x;   // NN*128 exact
    int j = idx & 127;
    float v = bf2f(h1[idx]);
    float vs = v * a1s[j];
    float vd = v * a1d[j];
    #pragma unroll
    for (int m = 1; m < 32; m <<= 1){ vs += __shfl_xor(vs, m); vd += __shfl_xor(vd, m); }
    if ((threadIdx.x & 31) == 0){
        int n = idx >> 7, h = j >> 5;
        al_s[n * 4 + h] = vs;
        al_d[n * 4 + h] = vd;
    }
}

__global__ __launch_bounds__(256) void k_al2(const float* __restrict__ h2a, const float* __restrict__ a2s,
                                             const float* __restrict__ a2d,
                                             float* __restrict__ al_s, float* __restrict__ al_d){
    int idx = blockIdx.x * 256 + threadIdx.x;   // NN*32 exact
    int c = idx & 31;
    float v = h2a[idx];
    float vs = v * a2s[c];
    float vd = v * a2d[c];
    #pragma unroll
    for (int m = 1; m < 32; m <<= 1){ vs += __shfl_xor(vs, m); vd += __shfl_xor(vd, m); }
    if ((threadIdx.x & 31) == 0){
        int n = idx >> 5;
        al_s[n] = vs;
        al_d[n] = vd;
    }
}

// ================= layer 1: per-node softmax + aggregate (wave per node) =================
// phase B: 4 edges in flight (16 lanes x 16B per h1 row)
__global__ __launch_bounds__(256) void k_node1(const int* __restrict__ src32, const ushort4* __restrict__ ale1p,
                                               const int* __restrict__ offsets,
                                               const float* __restrict__ al_s, const float* __restrict__ al_d,
                                               const u16* __restrict__ h1, const float* __restrict__ b1,
                                               u16* __restrict__ h1b, ushort4* __restrict__ pb1){
    int wave = threadIdx.x >> 6, lane = threadIdx.x & 63;
    int n = blockIdx.x * 4 + wave;               // 25000*4 = NN exact
    int start = offsets[n], end = offsets[n + 1];
    int degr = end - start - 1;
    f32x4 ald  = ((const f32x4*)al_d)[n];
    f32x4 alsn = ((const f32x4*)al_s)[n];
    float z0 = 0, z1 = 0, z2 = 0, z3 = 0, s0 = 0, s1 = 0, s2 = 0, s3 = 0;
    // phase A: numerators p_e (bf16) + denominators z + edge-logit sums (lane-parallel)
    for (int i = start + 1 + lane; i < end; i += 64){
        int src = src32[i];
        ushort4 av = ale1p[i];
        f32x4 als = ((const f32x4*)al_s)[src];
        float a0 = bf2f(av.x), a1 = bf2f(av.y), a2 = bf2f(av.z), a3 = bf2f(av.w);
        float e0 = __expf(lreluf(als[0] + ald[0] + a0));
        float e1 = __expf(lreluf(als[1] + ald[1] + a1));
        float e2 = __expf(lreluf(als[2] + ald[2] + a2));
        float e3 = __expf(lreluf(als[3] + ald[3] + a3));
        z0 += e0; z1 += e1; z2 += e2; z3 += e3;
        s0 += a0; s1 += a1; s2 += a2; s3 += a3;
        ushort4 w; w.x = f2bf(e0); w.y = f2bf(e1); w.z = f2bf(e2); w.w = f2bf(e3);
        pb1[i] = w;
    }
    #pragma unroll
    for (int m = 1; m < 64; m <<= 1){
        z0 += __shfl_xor(z0, m); z1 += __shfl_xor(z1, m); z2 += __shfl_xor(z2, m); z3 += __shfl_xor(z3, m);
        s0 += __shfl_xor(s0, m); s1 += __shfl_xor(s1, m); s2 += __shfl_xor(s2, m); s3 += __shfl_xor(s3, m);
    }
    float inv_deg = 1.f / fmaxf((float)degr, 1.f);
    float p0 = __expf(lreluf(alsn[0] + ald[0] + s0 * inv_deg)); z0 += p0;
    float p1 = __expf(lreluf(alsn[1] + ald[1] + s1 * inv_deg)); z1 += p1;
    float p2 = __expf(lreluf(alsn[2] + ald[2] + s2 * inv_deg)); z2 += p2;
    float p3 = __expf(lreluf(alsn[3] + ald[3] + s3 * inv_deg)); z3 += p3;
    // phase B: 4 quarter-waves process 4 edges concurrently; lane handles 8 channels
    int g = lane >> 4, l = lane & 15, hq = l >> 2;   // channels 8l..8l+7, head = l>>2
    float rz = 1.f / ((hq == 0) ? z0 : (hq == 1) ? z1 : (hq == 2) ? z2 : z3);
    float ps = (hq == 0) ? p0 : (hq == 1) ? p1 : (hq == 2) ? p2 : p3;
    const u32x4* h1v = (const u32x4*)h1;             // 16 u32x4 per row
    const u16* pbu = (const u16*)pb1;
    float acc[8];
    #pragma unroll
    for (int k = 0; k < 8; k++) acc[k] = 0.f;
    for (int i = start + g; i < end; i += 4){
        bool slf = (i == start);                     // group-uniform
        int src = slf ? n : src32[i];
        float p = slf ? ps : bf2f(pbu[(size_t)i * 4 + hq]);
        u32x4 v = h1v[(size_t)src * 16 + l];
        #pragma unroll
        for (int k = 0; k < 4; k++){
            acc[2 * k]     += p * bf2f((u16)(v[k] & 0xFFFFu));
            acc[2 * k + 1] += p * bf2f((u16)(v[k] >> 16));
        }
    }
    #pragma unroll
    for (int k = 0; k < 8; k++){
        acc[k] += __shfl_xor(acc[k], 16);
        acc[k] += __shfl_xor(acc[k], 32);
    }
    if (g == 0){
        u32x4 w;
        #pragma unroll
        for (int k = 0; k < 4; k++){
            float v0 = eluf(acc[2 * k]     * rz + b1[l * 8 + 2 * k]);
            float v1 = eluf(acc[2 * k + 1] * rz + b1[l * 8 + 2 * k + 1]);
            w[k] = (u32)f2bf(v0) | ((u32)f2bf(v1) << 16);
        }
        ((u32x4*)h1b)[(size_t)n * 16 + l] = w;
    }
}

// ================= layer 2: per-node softmax + aggregate + outputs =================
// phase B: 8 edges in flight (8 lanes x 16B per h2a row)
__global__ __launch_bounds__(256) void k_node2(const int* __restrict__ src32, const u16* __restrict__ ale2p,
                                               const int* __restrict__ perm, const int* __restrict__ offsets,
                                               const float* __restrict__ al_s, const float* __restrict__ al_d,
                                               const float* __restrict__ h2a, const float* __restrict__ b2,
                                               float* __restrict__ dout, u16* __restrict__ pb2){
    int wave = threadIdx.x >> 6, lane = threadIdx.x & 63;
    int n = blockIdx.x * 4 + wave;
    int start = offsets[n], end = offsets[n + 1];
    int degr = end - start - 1;
    float aldn = al_d[n];
    float z = 0.f, sa = 0.f;
    for (int i = start + 1 + lane; i < end; i += 64){
        int src = src32[i];
        float a = bf2f(ale2p[i]);
        float ev = __expf(lreluf(al_s[src] + aldn + a));
        z += ev; sa += a;
        pb2[i] = f2bf(ev);
    }
    #pragma unroll
    for (int m = 1; m < 64; m <<= 1){ z += __shfl_xor(z, m); sa += __shfl_xor(sa, m); }
    float mal = sa / fmaxf((float)degr, 1.f);
    float pself = __expf(lreluf(al_s[n] + aldn + mal));
    z += pself;
    float rz = 1.f / z;
    int g = lane >> 3, l = lane & 7;                 // channels l*4..l*4+3
    const f32x4* h2v = (const f32x4*)h2a;            // 8 f32x4 per row
    f32x4 acc = (f32x4){0.f, 0.f, 0.f, 0.f};
    for (int i = start + g; i < end; i += 8){
        bool slf = (i == start);                     // group-uniform
        int src = slf ? n : src32[i];
        float alpha = (slf ? pself : bf2f(pb2[i])) * rz;
        if (l == 0){
            int eo = slf ? (NE + n) : perm[i];
            dout[OUT_AL + eo] = alpha;
        }
        f32x4 v = h2v[(size_t)src * 8 + l];
        #pragma unroll
        for (int k = 0; k < 4; k++) acc[k] += alpha * v[k];
    }
    #pragma unroll
    for (int k = 0; k < 4; k++){
        acc[k] += __shfl_xor(acc[k], 8);
        acc[k] += __shfl_xor(acc[k], 16);
        acc[k] += __shfl_xor(acc[k], 32);
    }
    if (g == 0){
        f32x4 w;
        #pragma unroll
        for (int k = 0; k < 4; k++) w[k] = eluf(acc[k] + b2[l * 4 + k]);
        ((f32x4*)dout)[(size_t)n * 8 + l] = w;
    }
}

// ================= edge_index_sl output (f32 values) =================
__global__ __launch_bounds__(256) void k_eidx(const int* __restrict__ ei, float* __restrict__ dout){
    int i = blockIdx.x * 256 + threadIdx.x;
    if (i >= 2 * NE2) return;
    int val;
    if (i < NE2) val = (i < NE) ? ei[i] : (i - NE);
    else { int e = i - NE2; val = (e < NE) ? ei[NE + e] : (e - NE); }
    dout[OUT_EI + i] = (float)val;
}

extern "C" void kernel_launch(void* const* d_in, const int* in_sizes, int n_in,
                              void* d_out, int out_size, void* d_ws, size_t ws_size,
                              hipStream_t stream) {
    const float* x     = (const float*)d_in[0];
    const int*   ei    = (const int*)d_in[1];
    const float* eattr = (const float*)d_in[2];
    const float* W1    = (const float*)d_in[3];
    const float* W1e   = (const float*)d_in[4];
    const float* a1s   = (const float*)d_in[5];
    const float* a1d   = (const float*)d_in[6];
    const float* a1e   = (const float*)d_in[7];
    const float* b1    = (const float*)d_in[8];
    const float* W2    = (const float*)d_in[9];
    const float* W2e   = (const float*)d_in[10];
    const float* a2s   = (const float*)d_in[11];
    const float* a2d   = (const float*)d_in[12];
    const float* a2e   = (const float*)d_in[13];
    const float* b2    = (const float*)d_in[14];
    float* dout = (float*)d_out;

    char* ws = (char*)d_ws;
    size_t off = 0;
    auto alloc = [&](size_t bytes) -> void* {
        void* p = ws + off;
        off += (bytes + 255) & ~(size_t)255;
        return p;
    };
    // --- zero-initialized: deg only ---
    int* deg = (int*)alloc((size_t)NN * 4);
    size_t zero_bytes = off;
    // --- rest fully written before read ---
    int*     part    = (int*)alloc((size_t)NN * 4);
    int*     bsum    = (int*)alloc(512 * 4);
    int*     offsets = (int*)alloc((size_t)(NN + 1) * 4);
    int*     cursor  = (int*)alloc((size_t)NN * 4);
    int*     perm    = (int*)alloc((size_t)NE2 * 4);
    int*     src32   = (int*)alloc((size_t)NE2 * 4);
    ushort4* ale1p   = (ushort4*)alloc((size_t)NE2 * 8);
    u16*     ale2p   = (u16*)alloc((size_t)NE2 * 2);
    ushort4* pb1     = (ushort4*)alloc((size_t)NE2 * 8);
    float*   q1      = (float*)alloc(64 * 4);
    float*   q2      = (float*)alloc(16 * 4);
    u16*     ale1    = (u16*)alloc((size_t)NE * 4 * 2);   // dead after k_perm
    u16*     ale2    = (u16*)alloc((size_t)NE * 2);
    float*   al_s1   = (float*)alloc((size_t)NN * 4 * 4);
    float*   al_d1   = (float*)alloc((size_t)NN * 4 * 4);
    u16*     h1      = (u16*)alloc((size_t)NN * 128 * 2); // dead after k_node1
    u16*     h1b     = (u16*)alloc((size_t)NN * 128 * 2);
    // aliases into dead regions
    u16*   pb2   = (u16*)ale1;                            // NE2*2 = 3.4 MB <= 12.8 MB
    char*  h1r   = (char*)h1;
    float* h2a   = (float*)(h1r);                         // NN*32*4 = 12.8 MB
    float* al_s2 = (float*)(h1r + 12800000);              // NN*4
    float* al_d2 = (float*)(h1r + 13200128);              // NN*4

    const int TB = 256;
    hipMemsetAsync(d_ws, 0, zero_bytes, stream);

    // CSR build
    k_hist<<<NE / TB, TB, 0, stream>>>(ei, deg);
    k_scan_blk<<<NB_SCAN, TB, 0, stream>>>(deg, part, bsum);
    k_scan_top<<<1, 512, 0, stream>>>(bsum);
    k_scan_add<<<NB_SCAN, TB, 0, stream>>>(part, bsum, offsets, cursor, perm);
    // precomputes
    k_q<<<1, 64, 0, stream>>>(W1e, a1e, W2e, a2e, q1, q2);
    k_ale<<<NE * 4 / TB, TB, 0, stream>>>(eattr, q1, q2, ale1, ale2);
    k_scatter<<<NE / TB, TB, 0, stream>>>(ei, cursor, perm);
    k_perm<<<(NE2 + TB - 1) / TB, TB, 0, stream>>>(perm, ei, ale1, ale2, src32, ale1p, ale2p);
    // layer 1
    k_gemm1<<<(NN + 63) / 64, TB, 0, stream>>>(x, W1, h1);
    k_al1<<<NN * 128 / TB, TB, 0, stream>>>(h1, a1s, a1d, al_s1, al_d1);
    k_node1<<<NN / 4, TB, 0, stream>>>(src32, ale1p, offsets, al_s1, al_d1, h1, b1, h1b, pb1);
    // layer 2 (h1 region reused as h2a/al2; ale1 region reused as pb2)
    k_gemm2<<<(NN + 63) / 64, TB, 0, stream>>>(h1b, W2, h2a);
    k_al2<<<NN * 32 / TB, TB, 0, stream>>>(h2a, a2s, a2d, al_s2, al_d2);
    k_node2<<<NN / 4, TB, 0, stream>>>(src32, ale2p, perm, offsets, al_s2, al_d2, h2a, b2, dout, pb2);
    // edge index output
    k_eidx<<<(2 * NE2 + TB - 1) / TB, TB, 0, stream>>>(ei, dout);
}